// Round 3
// baseline (447.661 us; speedup 1.0000x reference)
//
#include <hip/hip_runtime.h>

// Conv x(32,64,128,128) * w(128,64,3,3) VALID + ReLU -> (32,128,126,126) flat.
// Implicit GEMM, bf16 MFMA 32x32x16, fp32 acc.
// Block = 2 output rows (oh, oh+1) x 128 kout x 126 sp, 4 waves.
// Wave w: kout half (w&1, 64 kouts as 2 strips of 32), output row (w>>1).
// All 4 needed x rows (oh..oh+3) staged ONCE into 64KB LDS -> single barrier,
// then 9 taps of barrier-free MFMA. Each ds_read_b128 B-frag feeds 2 MFMAs
// (2 kout strips) of 32x32x16 -> 64 FLOP/LDS-byte (2x the 16x16 layout).
// Reads at sp 128/129 (tap shift) clamp to row 127; they only touch output
// columns sp>=126 which are store-masked (MFMA is per-output-column).
// [R2 bench was an infra failure (container acquire); this is a resubmit.]

#define OUT0_SIZE (32 * 128 * 15876)

typedef __attribute__((ext_vector_type(8))) short short8v;     // 8 bf16 (4 VGPRs)
typedef __attribute__((ext_vector_type(16))) float float16v;   // MFMA 32x32 C/D

static __device__ __forceinline__ unsigned bf16_rn(float f) {
  unsigned u = __float_as_uint(f);
  u += 0x7FFFu + ((u >> 16) & 1u);   // RNE; inputs are finite normals
  return u >> 16;
}
static __device__ __forceinline__ unsigned pk2(float a, float b) {
  return bf16_rn(a) | (bf16_rn(b) << 16);
}

// Prepass: w[kout][c][r][s] fp32 -> wt[tap=r*3+s][kout][c] bf16 (147 KB, L2-resident)
__global__ void repack_w(const float* __restrict__ w, unsigned short* __restrict__ wt) {
  int o = blockIdx.x * 256 + threadIdx.x;       // 9*128*64 = 73728
  if (o >= 9 * 128 * 64) return;
  int tap  = o >> 13;
  int rem  = o & 8191;
  int kout = rem >> 6;
  int c    = rem & 63;
  wt[o] = (unsigned short)bf16_rn(w[kout * 576 + c * 9 + tap]);
}

__global__ __launch_bounds__(256, 2) void conv3x3_relu_mfma(
    const float* __restrict__ x, const unsigned short* __restrict__ wt,
    float* __restrict__ out) {
  // Bs[xrow 0..3][sp 0..127][64 c] bf16, 16B-chunk swizzle pos = ch ^ ((sp>>1)&7).
  __shared__ __align__(16) unsigned short Bs[4][128][64];   // 64 KB

  const int tid  = threadIdx.x;
  const int wv   = tid >> 6;
  const int lane = tid & 63;
  const int l31  = lane & 31;
  const int hb   = lane >> 5;

  // XCD-aware oh-pair swizzle: 8 consecutive pairs per XCD keep the 2-row
  // cross-block x reuse inside one XCD's L2.
  const int bx  = blockIdx.x;                // 0..63
  const int ohp = (bx & 7) * 8 + (bx >> 3);
  if (ohp >= 63) return;                     // 1 dead bx value
  const int n   = blockIdx.y;
  const int oh0 = ohp * 2;

  const int kh  = wv & 1;                    // kout half (64 kouts)
  const int ohs = wv >> 1;                   // which of the 2 output rows

  // ---- stage 4 x rows (oh0..oh0+3), 64 c each, once; 2-deep load pipeline ----
  const int spp = lane;                      // sp pair (coalesced float2)
  const int c8b = tid >> 6;                  // 0..3 (+4 on odd chunk)
  const float* xp = x + n * 1048576 + oh0 * 128 + 2 * spp;

  float2 v[2][8];
#define ISSUE(c, buf)                                                          \
  {                                                                            \
    const int xrow_ = (c) >> 1, c8_ = c8b + ((c) & 1) * 4;                     \
    _Pragma("unroll")                                                          \
    for (int j = 0; j < 8; ++j)                                                \
      buf[j] = *(const float2*)(xp + xrow_ * 128 + (c8_ * 8 + j) * 16384);     \
  }
  ISSUE(0, v[0]);
#pragma unroll
  for (int c = 0; c < 8; ++c) {
    if (c < 7) ISSUE(c + 1, v[(c + 1) & 1]);
    float2* vv = v[c & 1];
    const int xrow = c >> 1;
    const int c8   = c8b + (c & 1) * 4;
    const int pos  = c8 ^ (spp & 7);
    uint4 lo = make_uint4(pk2(vv[0].x, vv[1].x), pk2(vv[2].x, vv[3].x),
                          pk2(vv[4].x, vv[5].x), pk2(vv[6].x, vv[7].x));
    uint4 hi = make_uint4(pk2(vv[0].y, vv[1].y), pk2(vv[2].y, vv[3].y),
                          pk2(vv[4].y, vv[5].y), pk2(vv[6].y, vv[7].y));
    *(uint4*)&Bs[xrow][2 * spp][pos * 8]     = lo;
    *(uint4*)&Bs[xrow][2 * spp + 1][pos * 8] = hi;
  }
#undef ISSUE
  __syncthreads();                            // the ONLY barrier

  // ---- accumulators: 64 kout x 128 sp per wave = 128 f32/lane ----
  float16v acc[2][4];
#pragma unroll
  for (int st = 0; st < 2; ++st)
#pragma unroll
    for (int nt = 0; nt < 4; ++nt)
#pragma unroll
      for (int rg = 0; rg < 16; ++rg)
        acc[st][nt][rg] = 0.f;

  // A: wt[tap][kout][c]; lane holds A[m=l31][k=hb*8..+7] of each 32x16 frag.
  const unsigned short* wtk = wt + kh * 4096 + l31 * 64 + hb * 8;

#pragma unroll
  for (int r = 0; r < 3; ++r) {
#pragma unroll
    for (int s = 0; s < 3; ++s) {
      const int tap = r * 3 + s;
      short8v a[2][4];
#pragma unroll
      for (int st = 0; st < 2; ++st)
#pragma unroll
        for (int ks = 0; ks < 4; ++ks)
          a[st][ks] = *(const short8v*)(wtk + tap * 8192 + st * 2048 + ks * 16);

      const unsigned short* Bp = &Bs[ohs + r][0][0];
#pragma unroll
      for (int nt = 0; nt < 4; ++nt) {
        const int sp  = nt * 32 + l31 + s;
        const int spr = sp > 127 ? 127 : sp;   // clamp: only masked cols affected
        const int key = (spr >> 1) & 7;
#pragma unroll
        for (int ks = 0; ks < 4; ++ks) {
          const int pos = (ks * 2 + hb) ^ key;
          short8v b = *(const short8v*)(Bp + spr * 64 + pos * 8);
          acc[0][nt] = __builtin_amdgcn_mfma_f32_32x32x16_bf16(a[0][ks], b, acc[0][nt], 0, 0, 0);
          acc[1][nt] = __builtin_amdgcn_mfma_f32_32x32x16_bf16(a[1][ks], b, acc[1][nt], 0, 0, 0);
        }
      }
    }
  }

  // ---- epilogue: ReLU + store. C/D: col=l31 (sp), row=(rg&3)+8*(rg>>2)+4*hb ----
  const int ob = n * 128 * 15876 + (oh0 + ohs) * 126;
  const int kb = kh * 64 + 4 * hb;
#pragma unroll
  for (int st = 0; st < 2; ++st)
#pragma unroll
    for (int nt = 0; nt < 4; ++nt) {
      const int sp = nt * 32 + l31;
      if (sp < 126) {
#pragma unroll
        for (int rg = 0; rg < 16; ++rg) {
          const int kout = kb + st * 32 + (rg & 3) + 8 * (rg >> 2);
          out[ob + kout * 15876 + sp] = fmaxf(acc[st][nt][rg], 0.0f);
        }
      }
    }
}

// Output 1: concat(a,b) last dim -> (1024, 2048), float4 copy.
__global__ void concat_kernel(const float* __restrict__ a,
                              const float* __restrict__ b,
                              float* __restrict__ o) {
  int i   = blockIdx.x * 256 + threadIdx.x;  // 524288 float4
  int row = i >> 9;
  int col = i & 511;
  const float4* src = (col < 256) ? (const float4*)a + (row << 8) + col
                                  : (const float4*)b + (row << 8) + (col - 256);
  ((float4*)o)[i] = *src;
}

extern "C" void kernel_launch(void* const* d_in, const int* in_sizes, int n_in,
                              void* d_out, int out_size, void* d_ws, size_t ws_size,
                              hipStream_t stream) {
  const float* x = (const float*)d_in[0];
  const float* w = (const float*)d_in[1];
  const float* a = (const float*)d_in[2];
  const float* b = (const float*)d_in[3];

  float* out0 = (float*)d_out;
  float* out1 = out0 + OUT0_SIZE;
  unsigned short* wt = (unsigned short*)d_ws;   // 147456 B

  repack_w<<<288, 256, 0, stream>>>(w, wt);
  dim3 grid(64, 32);
  conv3x3_relu_mfma<<<grid, 256, 0, stream>>>(x, wt, out0);
  concat_kernel<<<2048, 256, 0, stream>>>(a, b, out1);
}